// Round 2
// baseline (516.431 us; speedup 1.0000x reference)
//
#include <hip/hip_runtime.h>
#include <hip/hip_bf16.h>

#define N_NODES 100000
#define N_EDGES 1600000
#define IN_FEA 128
#define HIDDEN 128
#define RANK 64

// ---------------- CSR build ----------------

__global__ void zero_int_kernel(int* __restrict__ p, int n) {
    int i = blockIdx.x * blockDim.x + threadIdx.x;
    if (i < n) p[i] = 0;
}

__global__ void count_deg_kernel(const int* __restrict__ dst, int* __restrict__ deg) {
    int e = blockIdx.x * blockDim.x + threadIdx.x;
    if (e < N_EDGES) atomicAdd(&deg[dst[e]], 1);
}

// 256 threads * 4 elems = 1024 elems per block
__global__ void scan_blocks_kernel(const int* __restrict__ deg, int* __restrict__ offs,
                                   int* __restrict__ blksums, int n) {
    __shared__ int sd[256];
    int t = threadIdx.x;
    int b = blockIdx.x;
    int i0 = b * 1024 + t * 4;
    int v0 = (i0 + 0 < n) ? deg[i0 + 0] : 0;
    int v1 = (i0 + 1 < n) ? deg[i0 + 1] : 0;
    int v2 = (i0 + 2 < n) ? deg[i0 + 2] : 0;
    int v3 = (i0 + 3 < n) ? deg[i0 + 3] : 0;
    int sum4 = v0 + v1 + v2 + v3;
    sd[t] = sum4;
    __syncthreads();
    for (int off = 1; off < 256; off <<= 1) {
        int add = 0;
        if (t >= off) add = sd[t - off];
        __syncthreads();
        sd[t] += add;
        __syncthreads();
    }
    int excl = sd[t] - sum4;   // exclusive prefix of thread sums
    int e0 = excl;
    int e1 = e0 + v0;
    int e2 = e1 + v1;
    int e3 = e2 + v2;
    if (i0 + 0 < n) offs[i0 + 0] = e0;
    if (i0 + 1 < n) offs[i0 + 1] = e1;
    if (i0 + 2 < n) offs[i0 + 2] = e2;
    if (i0 + 3 < n) offs[i0 + 3] = e3;
    if (t == 0) blksums[b] = sd[255];
}

__global__ void scan_partials_kernel(int* __restrict__ bs, int nb) {
    __shared__ int sd[128];
    int t = threadIdx.x;
    int v = (t < nb) ? bs[t] : 0;
    sd[t] = v;
    __syncthreads();
    for (int off = 1; off < 128; off <<= 1) {
        int add = 0;
        if (t >= off) add = sd[t - off];
        __syncthreads();
        sd[t] += add;
        __syncthreads();
    }
    if (t < nb) bs[t] = sd[t] - v;  // exclusive
}

__global__ void finalize_offs_kernel(int* __restrict__ offs, const int* __restrict__ bs,
                                     int* __restrict__ cursor, int n) {
    int i = blockIdx.x * blockDim.x + threadIdx.x;
    if (i < n) {
        int v = offs[i] + bs[i >> 10];
        offs[i] = v;
        cursor[i] = v;
    }
    if (i == 0) offs[n] = N_EDGES;
}

__global__ void scatter_kernel(const int* __restrict__ src, const int* __restrict__ dst,
                               int* __restrict__ cursor, int* __restrict__ eidx) {
    int e = blockIdx.x * blockDim.x + threadIdx.x;
    if (e < N_EDGES) {
        int d = dst[e];
        int pos = atomicAdd(&cursor[d], 1);
        eidx[pos] = src[e];
    }
}

// ---------------- GEMM1: h = x @ W  [N,128]x[128,64] ----------------
// block = 256 threads, 16 nodes/block. W staged in LDS (32KB).
// wave: 4 nodes x 16 lanes x 4 ranks.

__device__ __forceinline__ void fma4(float4& a, float s, const float4& b) {
    a.x = fmaf(s, b.x, a.x);
    a.y = fmaf(s, b.y, a.y);
    a.z = fmaf(s, b.z, a.z);
    a.w = fmaf(s, b.w, a.w);
}

__global__ __launch_bounds__(256) void gemm1_kernel(const float* __restrict__ x,
                                                    const float* __restrict__ W,
                                                    float* __restrict__ h) {
    __shared__ float Wl[IN_FEA * RANK];  // 32 KB
    int t = threadIdx.x;
    for (int i = t; i < IN_FEA * RANK; i += 256) Wl[i] = W[i];
    __syncthreads();

    int wave = t >> 6, lane = t & 63;
    int node = blockIdx.x * 16 + wave * 4 + (lane >> 4);
    int r0 = (lane & 15) * 4;

    const float4* x4 = (const float4*)(x + (long)node * IN_FEA);
    float4 acc = {0.f, 0.f, 0.f, 0.f};
    for (int k4 = 0; k4 < IN_FEA / 4; ++k4) {
        float4 xv = x4[k4];
        int kb = k4 * 4;
        float4 w0 = *(const float4*)&Wl[(kb + 0) * RANK + r0];
        float4 w1 = *(const float4*)&Wl[(kb + 1) * RANK + r0];
        float4 w2 = *(const float4*)&Wl[(kb + 2) * RANK + r0];
        float4 w3 = *(const float4*)&Wl[(kb + 3) * RANK + r0];
        fma4(acc, xv.x, w0);
        fma4(acc, xv.y, w1);
        fma4(acc, xv.z, w2);
        fma4(acc, xv.w, w3);
    }
    *(float4*)(h + (long)node * RANK + r0) = acc;
}

// ---------------- fused: product-aggregate + norm + out = trans @ V.T ----------------
// block = 256 threads (4 waves), 64 nodes/block.
// Phase A: wave w computes products for nodes [base+16w, base+16w+16), lane = rank.
// Phase B: wave w computes out rows for its 16 nodes, lane = hidden j (j and j+64).

__global__ __launch_bounds__(256) void agg_gemm2_kernel(const float* __restrict__ h,
                                                        const float* __restrict__ norm,
                                                        const float* __restrict__ V,
                                                        const int* __restrict__ offs,
                                                        const int* __restrict__ eidx,
                                                        float* __restrict__ out) {
    __shared__ float Vt[RANK * 129];        // V transposed, padded: 33,024 B
    __shared__ float pbuf[64 * RANK];       // 16,384 B
    int t = threadIdx.x;
    // load V [j][r] -> Vt[r*129 + j]
    for (int idx = t; idx < HIDDEN * RANK; idx += 256) {
        int j = idx >> 6, r = idx & 63;
        Vt[r * 129 + j] = V[idx];
    }

    int wave = t >> 6, lane = t & 63;
    int base = blockIdx.x * 64;

    // Phase A: segmented product over in-edges, direct fp32 product
    for (int i = 0; i < 16; ++i) {
        int nl = wave * 16 + i;
        int node = base + nl;
        float p = 1.0f;
        float nm = 0.0f;
        if (node < N_NODES) {
            int beg = offs[node], end = offs[node + 1];
            int e = beg;
            for (; e + 4 <= end; e += 4) {
                int s0 = eidx[e + 0], s1 = eidx[e + 1];
                int s2 = eidx[e + 2], s3 = eidx[e + 3];
                float a = h[(long)s0 * RANK + lane];
                float b = h[(long)s1 * RANK + lane];
                float c = h[(long)s2 * RANK + lane];
                float d = h[(long)s3 * RANK + lane];
                p *= a * b * c * d;
            }
            for (; e < end; ++e) p *= h[(long)eidx[e] * RANK + lane];
            nm = norm[node];
        }
        pbuf[nl * RANK + lane] = p * nm;
    }
    __syncthreads();

    // Phase B: out[node][j] = sum_r pbuf[node][r] * V[j][r]
    float acc0[16], acc1[16];
#pragma unroll
    for (int n = 0; n < 16; ++n) { acc0[n] = 0.f; acc1[n] = 0.f; }
    int g = wave * 16;
    for (int r4 = 0; r4 < RANK; r4 += 4) {
        float v0a = Vt[(r4 + 0) * 129 + lane], v0b = Vt[(r4 + 0) * 129 + 64 + lane];
        float v1a = Vt[(r4 + 1) * 129 + lane], v1b = Vt[(r4 + 1) * 129 + 64 + lane];
        float v2a = Vt[(r4 + 2) * 129 + lane], v2b = Vt[(r4 + 2) * 129 + 64 + lane];
        float v3a = Vt[(r4 + 3) * 129 + lane], v3b = Vt[(r4 + 3) * 129 + 64 + lane];
#pragma unroll
        for (int n = 0; n < 16; ++n) {
            float4 pr = *(const float4*)&pbuf[(g + n) * RANK + r4];
            acc0[n] = fmaf(pr.x, v0a, acc0[n]); acc1[n] = fmaf(pr.x, v0b, acc1[n]);
            acc0[n] = fmaf(pr.y, v1a, acc0[n]); acc1[n] = fmaf(pr.y, v1b, acc1[n]);
            acc0[n] = fmaf(pr.z, v2a, acc0[n]); acc1[n] = fmaf(pr.z, v2b, acc1[n]);
            acc0[n] = fmaf(pr.w, v3a, acc0[n]); acc1[n] = fmaf(pr.w, v3b, acc1[n]);
        }
    }
#pragma unroll
    for (int n = 0; n < 16; ++n) {
        int node = base + g + n;
        if (node < N_NODES) {
            out[(long)node * HIDDEN + lane]      = acc0[n];
            out[(long)node * HIDDEN + 64 + lane] = acc1[n];
        }
    }
}

// ---------------- launch ----------------

extern "C" void kernel_launch(void* const* d_in, const int* in_sizes, int n_in,
                              void* d_out, int out_size, void* d_ws, size_t ws_size,
                              hipStream_t stream) {
    const float* x    = (const float*)d_in[0];
    const float* norm = (const float*)d_in[1];
    const float* W    = (const float*)d_in[2];
    const float* V    = (const float*)d_in[3];
    const int*   src  = (const int*)d_in[4];
    const int*   dst  = (const int*)d_in[5];
    float* out = (float*)d_out;

    // workspace layout
    float* h      = (float*)d_ws;                     // N*RANK floats (25.6 MB)
    int*   deg    = (int*)(h + (long)N_NODES * RANK); // N
    int*   offs   = deg + N_NODES;                    // N+1
    int*   cursor = offs + N_NODES + 1;               // N
    int*   bsums  = cursor + N_NODES;                 // 128
    int*   eidx   = bsums + 128;                      // E

    const int NB_SCAN = (N_NODES + 1023) / 1024;      // 98
    const int GRID_N  = (N_NODES + 255) / 256;        // 391
    const int GRID_E  = (N_EDGES + 255) / 256;        // 6250

    zero_int_kernel<<<GRID_N, 256, 0, stream>>>(deg, N_NODES);
    count_deg_kernel<<<GRID_E, 256, 0, stream>>>(dst, deg);
    scan_blocks_kernel<<<NB_SCAN, 256, 0, stream>>>(deg, offs, bsums, N_NODES);
    scan_partials_kernel<<<1, 128, 0, stream>>>(bsums, NB_SCAN);
    finalize_offs_kernel<<<GRID_N, 256, 0, stream>>>(offs, bsums, cursor, N_NODES);
    scatter_kernel<<<GRID_E, 256, 0, stream>>>(src, dst, cursor, eidx);

    gemm1_kernel<<<N_NODES / 16, 256, 0, stream>>>(x, W, h);
    agg_gemm2_kernel<<<(N_NODES + 63) / 64, 256, 0, stream>>>(h, norm, V, offs, eidx, out);
}

// Round 3
// 437.843 us; speedup vs baseline: 1.1795x; 1.1795x over previous
//
#include <hip/hip_runtime.h>
#include <hip/hip_bf16.h>

#define N_NODES 100000
#define N_EDGES 1600000
#define IN_FEA 128
#define HIDDEN 128
#define RANK 64

// ---------------- CSR build ----------------

__global__ void count_deg_kernel(const int* __restrict__ dst, int* __restrict__ deg) {
    int i = blockIdx.x * blockDim.x + threadIdx.x;
    if (i < N_EDGES / 4) {
        int4 d = ((const int4*)dst)[i];
        atomicAdd(&deg[d.x], 1);
        atomicAdd(&deg[d.y], 1);
        atomicAdd(&deg[d.z], 1);
        atomicAdd(&deg[d.w], 1);
    }
}

// 256 threads * 4 elems = 1024 elems per block
__global__ void scan_blocks_kernel(const int* __restrict__ deg, int* __restrict__ offs,
                                   int* __restrict__ blksums, int n) {
    __shared__ int sd[256];
    int t = threadIdx.x;
    int b = blockIdx.x;
    int i0 = b * 1024 + t * 4;
    int v0 = (i0 + 0 < n) ? deg[i0 + 0] : 0;
    int v1 = (i0 + 1 < n) ? deg[i0 + 1] : 0;
    int v2 = (i0 + 2 < n) ? deg[i0 + 2] : 0;
    int v3 = (i0 + 3 < n) ? deg[i0 + 3] : 0;
    int sum4 = v0 + v1 + v2 + v3;
    sd[t] = sum4;
    __syncthreads();
    for (int off = 1; off < 256; off <<= 1) {
        int add = 0;
        if (t >= off) add = sd[t - off];
        __syncthreads();
        sd[t] += add;
        __syncthreads();
    }
    int excl = sd[t] - sum4;   // exclusive prefix of thread sums
    int e0 = excl;
    int e1 = e0 + v0;
    int e2 = e1 + v1;
    int e3 = e2 + v2;
    if (i0 + 0 < n) offs[i0 + 0] = e0;
    if (i0 + 1 < n) offs[i0 + 1] = e1;
    if (i0 + 2 < n) offs[i0 + 2] = e2;
    if (i0 + 3 < n) offs[i0 + 3] = e3;
    if (t == 0) blksums[b] = sd[255];
}

__global__ void scan_partials_kernel(int* __restrict__ bs, int nb) {
    __shared__ int sd[128];
    int t = threadIdx.x;
    int v = (t < nb) ? bs[t] : 0;
    sd[t] = v;
    __syncthreads();
    for (int off = 1; off < 128; off <<= 1) {
        int add = 0;
        if (t >= off) add = sd[t - off];
        __syncthreads();
        sd[t] += add;
        __syncthreads();
    }
    if (t < nb) bs[t] = sd[t] - v;  // exclusive
}

__global__ void finalize_offs_kernel(int* __restrict__ offs, const int* __restrict__ bs,
                                     int* __restrict__ cursor, int n) {
    int i = blockIdx.x * blockDim.x + threadIdx.x;
    if (i < n) {
        int v = offs[i] + bs[i >> 10];
        offs[i] = v;
        cursor[i] = v;
    }
    if (i == 0) offs[n] = N_EDGES;
}

__global__ void scatter_kernel(const int* __restrict__ src, const int* __restrict__ dst,
                               int* __restrict__ cursor, int* __restrict__ eidx) {
    int i = blockIdx.x * blockDim.x + threadIdx.x;
    if (i < N_EDGES / 4) {
        int4 s = ((const int4*)src)[i];
        int4 d = ((const int4*)dst)[i];
        eidx[atomicAdd(&cursor[d.x], 1)] = s.x;
        eidx[atomicAdd(&cursor[d.y], 1)] = s.y;
        eidx[atomicAdd(&cursor[d.z], 1)] = s.z;
        eidx[atomicAdd(&cursor[d.w], 1)] = s.w;
    }
}

// ---------------- GEMM1: h = x @ W  [N,128]x[128,64] ----------------
// block = 256 threads, 32 nodes/block. W staged in LDS (32KB).
// Each thread: 2 nodes x 4 ranks (W LDS reads amortized over 2 nodes).

__device__ __forceinline__ void fma4(float4& a, float s, const float4& b) {
    a.x = fmaf(s, b.x, a.x);
    a.y = fmaf(s, b.y, a.y);
    a.z = fmaf(s, b.z, a.z);
    a.w = fmaf(s, b.w, a.w);
}

__global__ __launch_bounds__(256) void gemm1_kernel(const float* __restrict__ x,
                                                    const float* __restrict__ W,
                                                    float* __restrict__ h) {
    __shared__ float Wl[IN_FEA * RANK];  // 32 KB
    int t = threadIdx.x;
    for (int i = t; i < IN_FEA * RANK; i += 256) Wl[i] = W[i];
    __syncthreads();

    int wave = t >> 6, lane = t & 63;
    int node0 = blockIdx.x * 32 + wave * 8 + (lane >> 4) * 2;
    int r0 = (lane & 15) * 4;

    const float4* xa = (const float4*)(x + (long)node0 * IN_FEA);
    const float4* xb = (const float4*)(x + (long)(node0 + 1) * IN_FEA);
    float4 acca = {0.f, 0.f, 0.f, 0.f};
    float4 accb = {0.f, 0.f, 0.f, 0.f};
    for (int k4 = 0; k4 < IN_FEA / 4; ++k4) {
        float4 va = xa[k4];
        float4 vb = xb[k4];
        int kb = k4 * 4;
        float4 w0 = *(const float4*)&Wl[(kb + 0) * RANK + r0];
        float4 w1 = *(const float4*)&Wl[(kb + 1) * RANK + r0];
        float4 w2 = *(const float4*)&Wl[(kb + 2) * RANK + r0];
        float4 w3 = *(const float4*)&Wl[(kb + 3) * RANK + r0];
        fma4(acca, va.x, w0); fma4(accb, vb.x, w0);
        fma4(acca, va.y, w1); fma4(accb, vb.y, w1);
        fma4(acca, va.z, w2); fma4(accb, vb.z, w2);
        fma4(acca, va.w, w3); fma4(accb, vb.w, w3);
    }
    *(float4*)(h + (long)node0 * RANK + r0) = acca;
    *(float4*)(h + (long)(node0 + 1) * RANK + r0) = accb;
}

// ---------------- aggregation: trans[n][r] = norm[n] * prod_e h[eidx[e]][r] ----------------
// One wave per node, lane = rank. No LDS -> high occupancy for gather-latency hiding.
// trans is stashed into out[n*128 + 0..64) to avoid extra workspace.

__global__ __launch_bounds__(256) void agg_kernel(const float* __restrict__ h,
                                                  const float* __restrict__ norm,
                                                  const int* __restrict__ offs,
                                                  const int* __restrict__ eidx,
                                                  float* __restrict__ out) {
    int wave = threadIdx.x >> 6, lane = threadIdx.x & 63;
    int node = blockIdx.x * 4 + wave;
    if (node >= N_NODES) return;
    int beg = offs[node], end = offs[node + 1];
    float p = 1.0f;
    for (int c = beg; c < end; c += 64) {
        int n = min(64, end - c);
        int sidx = (c + lane < end) ? eidx[c + lane] : 0;
        int j = 0;
        for (; j + 4 <= n; j += 4) {
            int s0 = __shfl(sidx, j + 0);
            int s1 = __shfl(sidx, j + 1);
            int s2 = __shfl(sidx, j + 2);
            int s3 = __shfl(sidx, j + 3);
            float a = h[(long)s0 * RANK + lane];
            float b = h[(long)s1 * RANK + lane];
            float cc = h[(long)s2 * RANK + lane];
            float d = h[(long)s3 * RANK + lane];
            p *= a * b * cc * d;
        }
        for (; j < n; ++j) {
            int s = __shfl(sidx, j);
            p *= h[(long)s * RANK + lane];
        }
    }
    out[(long)node * HIDDEN + lane] = p * norm[node];
}

// ---------------- GEMM2: out[n][j] = sum_r trans[n][r] * V[j][r] ----------------
// block = 256 (4 waves), 64 nodes/block. trans read from out[n*128+0..64), staged in LDS.

__global__ __launch_bounds__(256) void gemm2_kernel(const float* __restrict__ V,
                                                    float* __restrict__ out) {
    __shared__ float Vt[RANK * 129];        // V transposed, padded
    __shared__ float pbuf[64 * RANK];
    int t = threadIdx.x;
    for (int idx = t; idx < HIDDEN * RANK; idx += 256) {
        int j = idx >> 6, r = idx & 63;
        Vt[r * 129 + j] = V[idx];
    }

    int base = blockIdx.x * 64;
    // stage 64 trans rows (first 64 floats of each out row) into LDS, float4 chunks
    for (int idx = t; idx < 64 * RANK / 4; idx += 256) {
        int nl = idx >> 4;          // local node (16 float4 per row)
        int f4 = idx & 15;
        int node = base + nl;
        float4 v = {0.f, 0.f, 0.f, 0.f};
        if (node < N_NODES) v = *(const float4*)(out + (long)node * HIDDEN + f4 * 4);
        ((float4*)pbuf)[idx] = v;
    }
    __syncthreads();

    int wave = t >> 6, lane = t & 63;
    float acc0[16], acc1[16];
#pragma unroll
    for (int n = 0; n < 16; ++n) { acc0[n] = 0.f; acc1[n] = 0.f; }
    int g = wave * 16;
    for (int r4 = 0; r4 < RANK; r4 += 4) {
        float v0a = Vt[(r4 + 0) * 129 + lane], v0b = Vt[(r4 + 0) * 129 + 64 + lane];
        float v1a = Vt[(r4 + 1) * 129 + lane], v1b = Vt[(r4 + 1) * 129 + 64 + lane];
        float v2a = Vt[(r4 + 2) * 129 + lane], v2b = Vt[(r4 + 2) * 129 + 64 + lane];
        float v3a = Vt[(r4 + 3) * 129 + lane], v3b = Vt[(r4 + 3) * 129 + 64 + lane];
#pragma unroll
        for (int n = 0; n < 16; ++n) {
            float4 pr = *(const float4*)&pbuf[(g + n) * RANK + r4];
            acc0[n] = fmaf(pr.x, v0a, acc0[n]); acc1[n] = fmaf(pr.x, v0b, acc1[n]);
            acc0[n] = fmaf(pr.y, v1a, acc0[n]); acc1[n] = fmaf(pr.y, v1b, acc1[n]);
            acc0[n] = fmaf(pr.z, v2a, acc0[n]); acc1[n] = fmaf(pr.z, v2b, acc1[n]);
            acc0[n] = fmaf(pr.w, v3a, acc0[n]); acc1[n] = fmaf(pr.w, v3b, acc1[n]);
        }
    }
#pragma unroll
    for (int n = 0; n < 16; ++n) {
        int node = base + g + n;
        if (node < N_NODES) {
            out[(long)node * HIDDEN + lane]      = acc0[n];
            out[(long)node * HIDDEN + 64 + lane] = acc1[n];
        }
    }
}

// ---------------- launch ----------------

extern "C" void kernel_launch(void* const* d_in, const int* in_sizes, int n_in,
                              void* d_out, int out_size, void* d_ws, size_t ws_size,
                              hipStream_t stream) {
    const float* x    = (const float*)d_in[0];
    const float* norm = (const float*)d_in[1];
    const float* W    = (const float*)d_in[2];
    const float* V    = (const float*)d_in[3];
    const int*   src  = (const int*)d_in[4];
    const int*   dst  = (const int*)d_in[5];
    float* out = (float*)d_out;

    // workspace layout
    float* h      = (float*)d_ws;                     // N*RANK floats (25.6 MB)
    int*   deg    = (int*)(h + (long)N_NODES * RANK); // N
    int*   offs   = deg + N_NODES;                    // N+1
    int*   cursor = offs + N_NODES + 1;               // N
    int*   bsums  = cursor + N_NODES;                 // 128
    int*   eidx   = bsums + 128;                      // E

    const int NB_SCAN = (N_NODES + 1023) / 1024;      // 98
    const int GRID_N  = (N_NODES + 255) / 256;        // 391
    const int GRID_E4 = (N_EDGES / 4 + 255) / 256;    // 1563

    hipMemsetAsync(deg, 0, N_NODES * sizeof(int), stream);
    count_deg_kernel<<<GRID_E4, 256, 0, stream>>>(dst, deg);
    scan_blocks_kernel<<<NB_SCAN, 256, 0, stream>>>(deg, offs, bsums, N_NODES);
    scan_partials_kernel<<<1, 128, 0, stream>>>(bsums, NB_SCAN);
    finalize_offs_kernel<<<GRID_N, 256, 0, stream>>>(offs, bsums, cursor, N_NODES);
    scatter_kernel<<<GRID_E4, 256, 0, stream>>>(src, dst, cursor, eidx);

    gemm1_kernel<<<N_NODES / 32, 256, 0, stream>>>(x, W, h);
    agg_kernel<<<N_NODES / 4, 256, 0, stream>>>(h, norm, offs, eidx, out);
    gemm2_kernel<<<(N_NODES + 63) / 64, 256, 0, stream>>>(V, out);
}

// Round 4
// 331.962 us; speedup vs baseline: 1.5557x; 1.3190x over previous
//
#include <hip/hip_runtime.h>
#include <hip/hip_bf16.h>

#define N_NODES 100000
#define N_EDGES 1600000
#define IN_FEA 128
#define HIDDEN 128
#define RANK 64

#define NBUCK 391          // ceil(N_NODES/256): bucket b = nodes [b*256, b*256+256)
#define C_BLOCKS 1024
#define EPB 1563           // ceil(N_EDGES / C_BLOCKS)

// ---------------- CSR build: binned counting sort ----------------

// A: per-block bucket histogram -> blockhist row + global bucket totals
__global__ __launch_bounds__(256) void bucket_hist_kernel(const int* __restrict__ dst,
                                                          int* __restrict__ bhist,
                                                          int* __restrict__ blockhist) {
    __shared__ int hist[NBUCK];
    int t = threadIdx.x;
    for (int i = t; i < NBUCK; i += 256) hist[i] = 0;
    __syncthreads();
    int b0 = blockIdx.x * EPB;
    int b1 = min(b0 + EPB, N_EDGES);
    for (int e = b0 + t; e < b1; e += 256)
        atomicAdd(&hist[dst[e] >> 8], 1);
    __syncthreads();
    for (int i = t; i < NBUCK; i += 256) {
        int c = hist[i];
        blockhist[blockIdx.x * NBUCK + i] = c;
        if (c) atomicAdd(&bhist[i], c);
    }
}

// B: exclusive scan over 391 bucket totals
__global__ void bucket_scan_kernel(const int* __restrict__ bhist,
                                   int* __restrict__ bucket_offs,
                                   int* __restrict__ bucket_cursor,
                                   int* __restrict__ offs) {
    __shared__ int sd[512];
    int t = threadIdx.x;
    int v = (t < NBUCK) ? bhist[t] : 0;
    sd[t] = v;
    __syncthreads();
    for (int off = 1; off < 512; off <<= 1) {
        int a = 0;
        if (t >= off) a = sd[t - off];
        __syncthreads();
        sd[t] += a;
        __syncthreads();
    }
    if (t < NBUCK) {
        int excl = sd[t] - v;
        bucket_offs[t] = excl;
        bucket_cursor[t] = excl;
    }
    if (t == 0) {
        bucket_offs[NBUCK] = N_EDGES;
        offs[N_NODES] = N_EDGES;
    }
}

// C: reserve per-(block,bucket) ranges, scatter packed records (src<<8)|(dst&255)
__global__ __launch_bounds__(256) void binscatter_kernel(const int* __restrict__ src,
                                                         const int* __restrict__ dst,
                                                         const int* __restrict__ blockhist,
                                                         int* __restrict__ bucket_cursor,
                                                         unsigned* __restrict__ pairs) {
    __shared__ int wbase[NBUCK];
    __shared__ int cur[NBUCK];
    int t = threadIdx.x;
    for (int i = t; i < NBUCK; i += 256) {
        int c = blockhist[blockIdx.x * NBUCK + i];
        wbase[i] = c ? atomicAdd(&bucket_cursor[i], c) : 0;
        cur[i] = 0;
    }
    __syncthreads();
    int b0 = blockIdx.x * EPB;
    int b1 = min(b0 + EPB, N_EDGES);
    for (int e = b0 + t; e < b1; e += 256) {
        int d = dst[e];
        int s = src[e];
        int bk = d >> 8;
        int lp = atomicAdd(&cur[bk], 1);
        pairs[wbase[bk] + lp] = ((unsigned)s << 8) | (unsigned)(d & 255);
    }
}

// D: one block per bucket: local degree hist -> offs, then in-bucket scatter -> eidx
__global__ __launch_bounds__(256) void bucket_build_kernel(const unsigned* __restrict__ pairs,
                                                           const int* __restrict__ bucket_offs,
                                                           int* __restrict__ offs,
                                                           int* __restrict__ eidx) {
    __shared__ int dcnt[256];
    __shared__ int sd[256];
    __shared__ int cur[256];
    int b = blockIdx.x, t = threadIdx.x;
    int base = bucket_offs[b], end = bucket_offs[b + 1];
    dcnt[t] = 0;
    __syncthreads();
    for (int i = base + t; i < end; i += 256)
        atomicAdd(&dcnt[pairs[i] & 255u], 1);
    __syncthreads();
    int v = dcnt[t];
    sd[t] = v;
    __syncthreads();
    for (int off = 1; off < 256; off <<= 1) {
        int a = 0;
        if (t >= off) a = sd[t - off];
        __syncthreads();
        sd[t] += a;
        __syncthreads();
    }
    int excl = sd[t] - v;
    int node = b * 256 + t;
    if (node < N_NODES) offs[node] = base + excl;
    cur[t] = excl;
    __syncthreads();
    for (int i = base + t; i < end; i += 256) {
        unsigned r = pairs[i];
        int lp = atomicAdd(&cur[r & 255u], 1);
        eidx[base + lp] = (int)(r >> 8);
    }
}

// ---------------- GEMM1: h = x @ W  [N,128]x[128,64] ----------------

__device__ __forceinline__ void fma4(float4& a, float s, const float4& b) {
    a.x = fmaf(s, b.x, a.x);
    a.y = fmaf(s, b.y, a.y);
    a.z = fmaf(s, b.z, a.z);
    a.w = fmaf(s, b.w, a.w);
}

__global__ __launch_bounds__(256) void gemm1_kernel(const float* __restrict__ x,
                                                    const float* __restrict__ W,
                                                    float* __restrict__ h) {
    __shared__ float Wl[IN_FEA * RANK];  // 32 KB
    int t = threadIdx.x;
    for (int i = t; i < IN_FEA * RANK; i += 256) Wl[i] = W[i];
    __syncthreads();

    int wave = t >> 6, lane = t & 63;
    int node0 = blockIdx.x * 32 + wave * 8 + (lane >> 4) * 2;
    int r0 = (lane & 15) * 4;

    const float4* xa = (const float4*)(x + (long)node0 * IN_FEA);
    const float4* xb = (const float4*)(x + (long)(node0 + 1) * IN_FEA);
    float4 acca = {0.f, 0.f, 0.f, 0.f};
    float4 accb = {0.f, 0.f, 0.f, 0.f};
    for (int k4 = 0; k4 < IN_FEA / 4; ++k4) {
        float4 va = xa[k4];
        float4 vb = xb[k4];
        int kb = k4 * 4;
        float4 w0 = *(const float4*)&Wl[(kb + 0) * RANK + r0];
        float4 w1 = *(const float4*)&Wl[(kb + 1) * RANK + r0];
        float4 w2 = *(const float4*)&Wl[(kb + 2) * RANK + r0];
        float4 w3 = *(const float4*)&Wl[(kb + 3) * RANK + r0];
        fma4(acca, va.x, w0); fma4(accb, vb.x, w0);
        fma4(acca, va.y, w1); fma4(accb, vb.y, w1);
        fma4(acca, va.z, w2); fma4(accb, vb.z, w2);
        fma4(acca, va.w, w3); fma4(accb, vb.w, w3);
    }
    *(float4*)(h + (long)node0 * RANK + r0) = acca;
    *(float4*)(h + (long)(node0 + 1) * RANK + r0) = accb;
}

// ---------------- aggregation: one wave per node, lane = rank ----------------
// trans stashed into out[n*128 + 0..64)

__global__ __launch_bounds__(256) void agg_kernel(const float* __restrict__ h,
                                                  const float* __restrict__ norm,
                                                  const int* __restrict__ offs,
                                                  const int* __restrict__ eidx,
                                                  float* __restrict__ out) {
    int wave = threadIdx.x >> 6, lane = threadIdx.x & 63;
    int node = blockIdx.x * 4 + wave;
    if (node >= N_NODES) return;
    int beg = offs[node], end = offs[node + 1];
    float p = 1.0f;
    for (int c = beg; c < end; c += 64) {
        int n = min(64, end - c);
        int sidx = (c + lane < end) ? eidx[c + lane] : 0;
        int j = 0;
        for (; j + 4 <= n; j += 4) {
            int s0 = __shfl(sidx, j + 0);
            int s1 = __shfl(sidx, j + 1);
            int s2 = __shfl(sidx, j + 2);
            int s3 = __shfl(sidx, j + 3);
            float a = h[(long)s0 * RANK + lane];
            float b = h[(long)s1 * RANK + lane];
            float cc = h[(long)s2 * RANK + lane];
            float d = h[(long)s3 * RANK + lane];
            p *= a * b * cc * d;
        }
        for (; j < n; ++j) {
            int s = __shfl(sidx, j);
            p *= h[(long)s * RANK + lane];
        }
    }
    out[(long)node * HIDDEN + lane] = p * norm[node];
}

// ---------------- GEMM2: out[n][j] = sum_r trans[n][r] * V[j][r] ----------------

__global__ __launch_bounds__(256) void gemm2_kernel(const float* __restrict__ V,
                                                    float* __restrict__ out) {
    __shared__ float Vt[RANK * 129];
    __shared__ float pbuf[64 * RANK];
    int t = threadIdx.x;
    for (int idx = t; idx < HIDDEN * RANK; idx += 256) {
        int j = idx >> 6, r = idx & 63;
        Vt[r * 129 + j] = V[idx];
    }

    int base = blockIdx.x * 64;
    for (int idx = t; idx < 64 * RANK / 4; idx += 256) {
        int nl = idx >> 4;
        int f4 = idx & 15;
        int node = base + nl;
        float4 v = {0.f, 0.f, 0.f, 0.f};
        if (node < N_NODES) v = *(const float4*)(out + (long)node * HIDDEN + f4 * 4);
        ((float4*)pbuf)[idx] = v;
    }
    __syncthreads();

    int wave = t >> 6, lane = t & 63;
    float acc0[16], acc1[16];
#pragma unroll
    for (int n = 0; n < 16; ++n) { acc0[n] = 0.f; acc1[n] = 0.f; }
    int g = wave * 16;
    for (int r4 = 0; r4 < RANK; r4 += 4) {
        float v0a = Vt[(r4 + 0) * 129 + lane], v0b = Vt[(r4 + 0) * 129 + 64 + lane];
        float v1a = Vt[(r4 + 1) * 129 + lane], v1b = Vt[(r4 + 1) * 129 + 64 + lane];
        float v2a = Vt[(r4 + 2) * 129 + lane], v2b = Vt[(r4 + 2) * 129 + 64 + lane];
        float v3a = Vt[(r4 + 3) * 129 + lane], v3b = Vt[(r4 + 3) * 129 + 64 + lane];
#pragma unroll
        for (int n = 0; n < 16; ++n) {
            float4 pr = *(const float4*)&pbuf[(g + n) * RANK + r4];
            acc0[n] = fmaf(pr.x, v0a, acc0[n]); acc1[n] = fmaf(pr.x, v0b, acc1[n]);
            acc0[n] = fmaf(pr.y, v1a, acc0[n]); acc1[n] = fmaf(pr.y, v1b, acc1[n]);
            acc0[n] = fmaf(pr.z, v2a, acc0[n]); acc1[n] = fmaf(pr.z, v2b, acc1[n]);
            acc0[n] = fmaf(pr.w, v3a, acc0[n]); acc1[n] = fmaf(pr.w, v3b, acc1[n]);
        }
    }
#pragma unroll
    for (int n = 0; n < 16; ++n) {
        int node = base + g + n;
        if (node < N_NODES) {
            out[(long)node * HIDDEN + lane]      = acc0[n];
            out[(long)node * HIDDEN + 64 + lane] = acc1[n];
        }
    }
}

// ---------------- launch ----------------

extern "C" void kernel_launch(void* const* d_in, const int* in_sizes, int n_in,
                              void* d_out, int out_size, void* d_ws, size_t ws_size,
                              hipStream_t stream) {
    const float* x    = (const float*)d_in[0];
    const float* norm = (const float*)d_in[1];
    const float* W    = (const float*)d_in[2];
    const float* V    = (const float*)d_in[3];
    const int*   src  = (const int*)d_in[4];
    const int*   dst  = (const int*)d_in[5];
    float* out = (float*)d_out;

    // workspace layout (ws): h, offs, eidx, small bucket arrays
    float* h           = (float*)d_ws;                       // N*RANK floats (25.6 MB)
    int*   offs        = (int*)(h + (long)N_NODES * RANK);   // N+1
    int*   eidx        = offs + N_NODES + 1;                 // E
    int*   bhist       = eidx + N_EDGES;                     // NBUCK
    int*   bucket_offs = bhist + NBUCK;                      // NBUCK+1
    int*   bucket_cur  = bucket_offs + NBUCK + 1;            // NBUCK

    // scratch inside d_out (dead until agg_kernel writes trans):
    unsigned* pairs    = (unsigned*)d_out;                   // E uint32 (6.4 MB)
    int*     blockhist = (int*)d_out + 2097152;              // at +8 MB: C_BLOCKS*NBUCK ints (1.6 MB)

    hipMemsetAsync(bhist, 0, NBUCK * sizeof(int), stream);
    bucket_hist_kernel<<<C_BLOCKS, 256, 0, stream>>>(dst, bhist, blockhist);
    bucket_scan_kernel<<<1, 512, 0, stream>>>(bhist, bucket_offs, bucket_cur, offs);
    binscatter_kernel<<<C_BLOCKS, 256, 0, stream>>>(src, dst, blockhist, bucket_cur, pairs);
    bucket_build_kernel<<<NBUCK, 256, 0, stream>>>(pairs, bucket_offs, offs, eidx);

    gemm1_kernel<<<N_NODES / 32, 256, 0, stream>>>(x, W, h);
    agg_kernel<<<N_NODES / 4, 256, 0, stream>>>(h, norm, offs, eidx, out);
    gemm2_kernel<<<(N_NODES + 63) / 64, 256, 0, stream>>>(V, out);
}